// Round 1
// baseline (316.571 us; speedup 1.0000x reference)
//
#include <hip/hip_runtime.h>
#include <math.h>

#define EPSF 1e-7f
#define YMAXF 0.99999f   // fp32(1 - 1e-5), same rounding as jnp clip constant
#define WPITCH 136       // bf16 pitch: 272 B/row -> <=2-way bank alias (free)

#define NBUCK 256        // dst buckets: bucket = dst >> 9 (needs N <= 131072)
#define PB_CHUNK 2048    // edges per bucket_scatter block

typedef short bf16x8 __attribute__((ext_vector_type(8)));
typedef short bf16x4 __attribute__((ext_vector_type(4)));
typedef float f32x4  __attribute__((ext_vector_type(4)));
typedef int   i32x4  __attribute__((ext_vector_type(4)));

__device__ __forceinline__ float grp32_sum(float v) {
    v += __shfl_xor(v, 1);
    v += __shfl_xor(v, 2);
    v += __shfl_xor(v, 4);
    v += __shfl_xor(v, 8);
    v += __shfl_xor(v, 16);
    return v;
}

__device__ __forceinline__ short f2bf(float f) {
    unsigned u = __float_as_uint(f);
    unsigned r = (u + 0x7FFFu + ((u >> 16) & 1u)) >> 16;
    return (short)r;
}

__device__ __forceinline__ float bf2f(short u) {
    return __uint_as_float(((unsigned)(unsigned short)u) << 16);
}

// low/high bf16 of a packed dword -> float (identical value to bf2f of the shorts)
__device__ __forceinline__ float bf_lo(int w) {
    return __uint_as_float(((unsigned)w) << 16);
}
__device__ __forceinline__ float bf_hi(int w) {
    return __uint_as_float(((unsigned)w) & 0xffff0000u);
}

// Kernel 1: v = log_map_zero(x), stored bf16 (halves gather-side bytes)
__global__ void logmap_kernel(const float* __restrict__ x,
                              const float* __restrict__ c_ptr,
                              short* __restrict__ v_bf,
                              int N) {
    int gid = blockIdx.x * blockDim.x + threadIdx.x;
    int row = gid >> 5;
    if (row >= N) return;
    int lane = gid & 31;
    const float4 xv = ((const float4*)x)[(size_t)row * 32 + lane];
    float ss = xv.x * xv.x + xv.y * xv.y + xv.z * xv.z + xv.w * xv.w;
    ss = grp32_sum(ss);
    float sc = sqrtf(c_ptr[0]);
    float xn = fmaxf(sqrtf(ss), EPSF);
    float y = fminf(sc * xn, YMAXF);
    float s = atanhf(y) / (sc * xn);
    bf16x4 pk;
    pk[0] = f2bf(s * xv.x); pk[1] = f2bf(s * xv.y);
    pk[2] = f2bf(s * xv.z); pk[3] = f2bf(s * xv.w);
    *(bf16x4*)&v_bf[(size_t)row * 128 + lane * 4] = pk;
}

// Pass A: count edges per coarse bucket (bucket = dst>>9)
__global__ __launch_bounds__(256)
void bucket_count_kernel(const int* __restrict__ eidx_dst,
                         int* __restrict__ bucketCount, int E) {
    __shared__ int h[NBUCK];
    int tid = threadIdx.x;
    h[tid] = 0;
    __syncthreads();
    int per = (E + gridDim.x - 1) / gridDim.x;
    int start = blockIdx.x * per;
    int end = min(start + per, E);
    for (int i = start + tid; i < end; i += 256)
        atomicAdd(&h[eidx_dst[i] >> 9], 1);
    __syncthreads();
    if (h[tid]) atomicAdd(&bucketCount[tid], h[tid]);
}

// Scan of 256 bucket counts -> bucket_base (exclusive) and cursor copy
__global__ __launch_bounds__(256)
void bucket_scan_kernel(const int* __restrict__ bucketCount,
                        int* __restrict__ bucket_base,
                        int* __restrict__ cursor) {
    __shared__ int part[256];
    int tid = threadIdx.x;
    int val = bucketCount[tid];
    part[tid] = val;
    __syncthreads();
    for (int off = 1; off < 256; off <<= 1) {
        int t = (tid >= off) ? part[tid - off] : 0;
        __syncthreads();
        part[tid] += t;
        __syncthreads();
    }
    int excl = part[tid] - val;
    bucket_base[tid] = excl;
    cursor[tid] = excl;
}

// Pass B: partition edges into coarse buckets (LDS counting sort, run-grouped writes)
__global__ __launch_bounds__(256)
void bucket_scatter_kernel(const int* __restrict__ eidx,
                           int* __restrict__ cursor,
                           int* __restrict__ bucketed, int E) {
    __shared__ int hist[NBUCK];
    __shared__ int lstart[NBUCK];
    __shared__ int gbase[NBUCK];
    __shared__ int part[256];
    __shared__ int stage[PB_CHUNK];
    __shared__ unsigned char stageB[PB_CHUNK];

    int tid = threadIdx.x;
    int start = blockIdx.x * PB_CHUNK;
    int cnt = min(PB_CHUNK, E - start);
    hist[tid] = 0;
    __syncthreads();

    const int J = PB_CHUNK / 256;
    int myP[J], myB[J], myR[J];
    #pragma unroll
    for (int j = 0; j < J; ++j) {
        int idx = j * 256 + tid;
        myR[j] = -1;
        if (idx < cnt) {
            int e = start + idx;
            int d = eidx[E + e];
            int s = eidx[e];
            int b = d >> 9;
            myB[j] = b;
            myP[j] = ((d & 511) << 17) | s;
            myR[j] = atomicAdd(&hist[b], 1);
        }
    }
    __syncthreads();
    part[tid] = hist[tid];
    __syncthreads();
    for (int off = 1; off < 256; off <<= 1) {
        int t = (tid >= off) ? part[tid - off] : 0;
        __syncthreads();
        part[tid] += t;
        __syncthreads();
    }
    lstart[tid] = part[tid] - hist[tid];
    if (hist[tid]) gbase[tid] = atomicAdd(&cursor[tid], hist[tid]);
    __syncthreads();
    #pragma unroll
    for (int j = 0; j < J; ++j) {
        if (myR[j] >= 0) {
            int pos = lstart[myB[j]] + myR[j];
            stage[pos] = myP[j];
            stageB[pos] = (unsigned char)myB[j];
        }
    }
    __syncthreads();
    for (int i = tid; i < cnt; i += 256) {
        int b = stageB[i];
        bucketed[gbase[b] + (i - lstart[b])] = stage[i];
    }
}

// Pass C: per-bucket fine partition -> CSR (offsets = segment start, deg)
__global__ __launch_bounds__(256)
void csr_kernel(const int* __restrict__ bucketed,
                const int* __restrict__ bucket_base,
                const int* __restrict__ cursor_post,
                int* __restrict__ offsets, int* __restrict__ deg,
                int* __restrict__ sorted_src, int N) {
    __shared__ int hist[512];
    __shared__ int pre[512];
    __shared__ int cur[512];
    __shared__ int part[256];
    int b = blockIdx.x;
    int tid = threadIdx.x;
    int start = bucket_base[b];
    int end = cursor_post[b];
    hist[tid] = 0;
    hist[tid + 256] = 0;
    __syncthreads();
    for (int i = start + tid; i < end; i += 256)
        atomicAdd(&hist[bucketed[i] >> 17], 1);
    __syncthreads();
    int a0 = hist[2 * tid], a1 = hist[2 * tid + 1];
    part[tid] = a0 + a1;
    __syncthreads();
    for (int off = 1; off < 256; off <<= 1) {
        int t = (tid >= off) ? part[tid - off] : 0;
        __syncthreads();
        part[tid] += t;
        __syncthreads();
    }
    int base2 = part[tid] - (a0 + a1);
    pre[2 * tid] = base2;
    pre[2 * tid + 1] = base2 + a0;
    cur[2 * tid] = base2;
    cur[2 * tid + 1] = base2 + a0;
    __syncthreads();
    int node0 = b << 9;
    for (int i = tid; i < 512; i += 256) {
        int node = node0 + i;
        if (node < N) { offsets[node] = start + pre[i]; deg[node] = hist[i]; }
    }
    for (int i = start + tid; i < end; i += 256) {
        int p = bucketed[i];
        int ld = p >> 17;
        int src = p & 0x1FFFF;
        int r = atomicAdd(&cur[ld], 1);
        sorted_src[start + r] = src;
    }
}

// Fused gather + MFMA epilogue, restructured for latency tolerance:
//  - 256 threads = 16 groups of 16 lanes; each group gathers FOUR dst rows
//    (rows base+t*16+g, t=0..3) with NO barriers between rows, issuing 16
//    independent 16B gather loads per chunk (r[16] register array -> MLP 16).
//  - ONE __syncthreads, then each wave runs the full 16x128 MFMA tile for its
//    own 16 rows; out-norm reduction is in-wave via shfl_xor (no LDS, no
//    epilogue barriers).  2 barriers per block total (was 3 per 16-row tile).
__global__ __launch_bounds__(256, 3)
void gather_epilogue_kernel(const short* __restrict__ v_bf,
                            const int* __restrict__ sorted_src,
                            const int* __restrict__ offsets,
                            const int* __restrict__ deg,
                            const float* __restrict__ W,
                            const float* __restrict__ bias,
                            const float* __restrict__ c_ptr,
                            float* __restrict__ out,
                            int N) {
    __shared__ short Wl[128 * WPITCH];    // 34816 B
    __shared__ short v2l[64 * WPITCH];    // 17408 B  (4 tiles x 16 rows)

    int tid = threadIdx.x;
    // stage W -> LDS bf16 (read once per block from L2)
    for (int i = tid; i < 4096; i += 256) {
        float4 w4 = ((const float4*)W)[i];
        int o = i >> 5;
        int k = (i & 31) * 4;
        bf16x4 w;
        w[0] = f2bf(w4.x); w[1] = f2bf(w4.y); w[2] = f2bf(w4.z); w[3] = f2bf(w4.w);
        *(bf16x4*)&Wl[o * WPITCH + k] = w;
    }

    int wave = tid >> 6;
    int lane = tid & 63;
    int quad = lane >> 4;
    int l16  = lane & 15;
    int g  = tid >> 4;        // gather group (0..15)
    int gl = tid & 15;        // lane in group
    float sc = sqrtf(c_ptr[0]);

    // per-lane bias for the 8 col-tiles this wave's rows need (col = c*16+l16)
    float bsv[8];
    #pragma unroll
    for (int c = 0; c < 8; ++c) bsv[c] = bias[c * 16 + l16];

    int row_base = blockIdx.x * 64;

    // ---- gather phase: 4 rows per group, barrier-free ----
    for (int t = 0; t < 4; ++t) {
        int row = row_base + t * 16 + g;
        bool valid = (row < N);
        float acc[8];
        #pragma unroll
        for (int i = 0; i < 8; ++i) acc[i] = 0.0f;
        int start = 0, d = 0;
        if (valid) {
            start = offsets[row];
            d = deg[row];
            bf16x8 r0 = *(const bf16x8*)&v_bf[(size_t)row * 128 + gl * 8];
            i32x4 w0 = *(const i32x4*)&r0;
            #pragma unroll
            for (int k2 = 0; k2 < 4; ++k2) {
                acc[2 * k2]     = bf_lo(w0[k2]);
                acc[2 * k2 + 1] = bf_hi(w0[k2]);
            }
        }
        for (int j = 0; j < d; j += 16) {
            int m = d - j;                              // group-uniform
            int idx = j + gl;
            int batch = sorted_src[start + min(idx, d - 1)];
            bf16x8 r[16];
            #pragma unroll
            for (int jj = 0; jj < 16; ++jj) {
                if (jj < m) {                           // uniform within group
                    int src = __shfl(batch, (lane & 48) | jj);
                    r[jj] = *(const bf16x8*)&v_bf[(size_t)src * 128 + gl * 8];
                }
            }
            #pragma unroll
            for (int jj = 0; jj < 16; ++jj) {
                if (jj < m) {
                    i32x4 wv = *(const i32x4*)&r[jj];
                    #pragma unroll
                    for (int k2 = 0; k2 < 4; ++k2) {
                        acc[2 * k2]     += bf_lo(wv[k2]);
                        acc[2 * k2 + 1] += bf_hi(wv[k2]);
                    }
                }
            }
        }
        float inv = 1.0f / (float)(d + 1);
        #pragma unroll
        for (int i = 0; i < 8; ++i) acc[i] *= inv;

        // row sumsq across the 16-lane group
        float ss = 0.0f;
        #pragma unroll
        for (int i = 0; i < 8; ++i) ss += acc[i] * acc[i];
        ss += __shfl_xor(ss, 1);
        ss += __shfl_xor(ss, 2);
        ss += __shfl_xor(ss, 4);
        ss += __shfl_xor(ss, 8);

        // exp_map_zero then log_map_zero scale (redundant per lane)
        float vn  = sqrtf(ss);
        float vnc = fmaxf(vn, EPSF);
        float th  = tanhf(sc * vnc);
        float tt  = th / (sc * vnc);          // x_hyp = tt * v_agg
        float hn  = fmaxf(th / sc, EPSF);
        float y2  = fminf(sc * hn, YMAXF);
        float s2  = atanhf(y2) / (sc * hn);   // v2 = s2 * x_hyp
        float scale = s2 * tt;

        bf16x8 pk;
        #pragma unroll
        for (int i = 0; i < 8; ++i) pk[i] = f2bf(acc[i] * scale);
        *(bf16x8*)&v2l[(t * 16 + g) * WPITCH + gl * 8] = pk;
    }
    __syncthreads();

    // ---- MFMA phase: wave w owns tile w (16 rows x 128 cols) ----
    f32x4 acc2[8];
    #pragma unroll
    for (int c = 0; c < 8; ++c) acc2[c] = (f32x4){bsv[c], bsv[c], bsv[c], bsv[c]};
    #pragma unroll
    for (int k0 = 0; k0 < 128; k0 += 32) {
        bf16x8 af = *(const bf16x8*)&v2l[(wave * 16 + l16) * WPITCH + k0 + quad * 8];
        #pragma unroll
        for (int c = 0; c < 8; ++c) {
            bf16x8 bf = *(const bf16x8*)&Wl[(c * 16 + l16) * WPITCH + k0 + quad * 8];
            acc2[c] = __builtin_amdgcn_mfma_f32_16x16x32_bf16(af, bf, acc2[c], 0, 0, 0);
        }
    }

    // out-norm + exp_map store, fully in-wave: D(row=quad*4+r, col=c*16+l16)
    #pragma unroll
    for (int r = 0; r < 4; ++r) {
        float ss = 0.0f;
        #pragma unroll
        for (int c = 0; c < 8; ++c) ss += acc2[c][r] * acc2[c][r];
        ss += __shfl_xor(ss, 1);
        ss += __shfl_xor(ss, 2);
        ss += __shfl_xor(ss, 4);
        ss += __shfl_xor(ss, 8);
        float on  = sqrtf(ss);
        float onc = fmaxf(on, EPSF);
        float gsc = tanhf(sc * onc) / (sc * onc);
        int orow = row_base + wave * 16 + quad * 4 + r;
        if (orow < N) {
            size_t base = (size_t)orow * 128;
            #pragma unroll
            for (int c = 0; c < 8; ++c)
                out[base + c * 16 + l16] = gsc * acc2[c][r];
        }
    }
}

extern "C" void kernel_launch(void* const* d_in, const int* in_sizes, int n_in,
                              void* d_out, int out_size, void* d_ws, size_t ws_size,
                              hipStream_t stream) {
    const float* x     = (const float*)d_in[0];
    const int*   eidx  = (const int*)d_in[1];
    const float* c_ptr = (const float*)d_in[2];
    const float* W     = (const float*)d_in[4];
    const float* bias  = (const float*)d_in[5];
    float* out = (float*)d_out;

    int N = in_sizes[0] / 128;
    int E = in_sizes[1] / 2;

    short* v_bf        = (short*)d_ws;                     // N*128 bf16
    int*   deg         = (int*)(v_bf + (size_t)N * 128);   // N
    int*   offsets     = deg + N;                          // N
    int*   bucketCount = offsets + N;                      // NBUCK
    int*   bucket_base = bucketCount + NBUCK;              // NBUCK
    int*   cursor      = bucket_base + NBUCK;              // NBUCK
    int*   bucketed    = cursor + NBUCK;                   // E (packed)
    int*   sorted_src  = bucketed + E;                     // E

    hipMemsetAsync(bucketCount, 0, NBUCK * sizeof(int), stream);

    {
        long long threads = (long long)N * 32;
        int blocks = (int)((threads + 255) / 256);
        hipLaunchKernelGGL(logmap_kernel, dim3(blocks), dim3(256), 0, stream,
                           x, c_ptr, v_bf, N);
    }
    hipLaunchKernelGGL(bucket_count_kernel, dim3(256), dim3(256), 0, stream,
                       eidx + E, bucketCount, E);
    hipLaunchKernelGGL(bucket_scan_kernel, dim3(1), dim3(256), 0, stream,
                       bucketCount, bucket_base, cursor);
    {
        int blocks = (E + PB_CHUNK - 1) / PB_CHUNK;
        hipLaunchKernelGGL(bucket_scatter_kernel, dim3(blocks), dim3(256), 0, stream,
                           eidx, cursor, bucketed, E);
    }
    {
        int blocks = (N + 511) / 512;
        hipLaunchKernelGGL(csr_kernel, dim3(blocks), dim3(256), 0, stream,
                           bucketed, bucket_base, cursor, offsets, deg, sorted_src, N);
    }
    {
        int blocks = (N + 63) / 64;
        hipLaunchKernelGGL(gather_epilogue_kernel, dim3(blocks), dim3(256), 0, stream,
                           v_bf, sorted_src, offsets, deg, W, bias, c_ptr, out, N);
    }
}

// Round 2
// 266.821 us; speedup vs baseline: 1.1865x; 1.1865x over previous
//
#include <hip/hip_runtime.h>
#include <math.h>

#define EPSF 1e-7f
#define YMAXF 0.99999f   // fp32(1 - 1e-5), same rounding as jnp clip constant
#define WPITCH 136       // bf16 pitch: 272 B/row -> <=2-way bank alias (free)

#define NBUCK 256        // dst buckets: bucket = dst >> 9 (needs N <= 131072)
#define PB_CHUNK 2048    // edges per bucket_scatter block

typedef short bf16x8 __attribute__((ext_vector_type(8)));
typedef short bf16x4 __attribute__((ext_vector_type(4)));
typedef float f32x4  __attribute__((ext_vector_type(4)));
typedef int   i32x4  __attribute__((ext_vector_type(4)));

__device__ __forceinline__ float grp32_sum(float v) {
    v += __shfl_xor(v, 1);
    v += __shfl_xor(v, 2);
    v += __shfl_xor(v, 4);
    v += __shfl_xor(v, 8);
    v += __shfl_xor(v, 16);
    return v;
}

__device__ __forceinline__ short f2bf(float f) {
    unsigned u = __float_as_uint(f);
    unsigned r = (u + 0x7FFFu + ((u >> 16) & 1u)) >> 16;
    return (short)r;
}

__device__ __forceinline__ float bf2f(short u) {
    return __uint_as_float(((unsigned)(unsigned short)u) << 16);
}

// low/high bf16 of a packed dword -> float (identical value to bf2f of the shorts)
__device__ __forceinline__ float bf_lo(int w) {
    return __uint_as_float(((unsigned)w) << 16);
}
__device__ __forceinline__ float bf_hi(int w) {
    return __uint_as_float(((unsigned)w) & 0xffff0000u);
}

// Kernel 1: v = log_map_zero(x), stored bf16 (halves gather-side bytes)
__global__ void logmap_kernel(const float* __restrict__ x,
                              const float* __restrict__ c_ptr,
                              short* __restrict__ v_bf,
                              int N) {
    int gid = blockIdx.x * blockDim.x + threadIdx.x;
    int row = gid >> 5;
    if (row >= N) return;
    int lane = gid & 31;
    const float4 xv = ((const float4*)x)[(size_t)row * 32 + lane];
    float ss = xv.x * xv.x + xv.y * xv.y + xv.z * xv.z + xv.w * xv.w;
    ss = grp32_sum(ss);
    float sc = sqrtf(c_ptr[0]);
    float xn = fmaxf(sqrtf(ss), EPSF);
    float y = fminf(sc * xn, YMAXF);
    float s = atanhf(y) / (sc * xn);
    bf16x4 pk;
    pk[0] = f2bf(s * xv.x); pk[1] = f2bf(s * xv.y);
    pk[2] = f2bf(s * xv.z); pk[3] = f2bf(s * xv.w);
    *(bf16x4*)&v_bf[(size_t)row * 128 + lane * 4] = pk;
}

// Pass A: count edges per coarse bucket (bucket = dst>>9)
__global__ __launch_bounds__(256)
void bucket_count_kernel(const int* __restrict__ eidx_dst,
                         int* __restrict__ bucketCount, int E) {
    __shared__ int h[NBUCK];
    int tid = threadIdx.x;
    h[tid] = 0;
    __syncthreads();
    int per = (E + gridDim.x - 1) / gridDim.x;
    int start = blockIdx.x * per;
    int end = min(start + per, E);
    for (int i = start + tid; i < end; i += 256)
        atomicAdd(&h[eidx_dst[i] >> 9], 1);
    __syncthreads();
    if (h[tid]) atomicAdd(&bucketCount[tid], h[tid]);
}

// Scan of 256 bucket counts -> bucket_base (exclusive) and cursor copy
__global__ __launch_bounds__(256)
void bucket_scan_kernel(const int* __restrict__ bucketCount,
                        int* __restrict__ bucket_base,
                        int* __restrict__ cursor) {
    __shared__ int part[256];
    int tid = threadIdx.x;
    int val = bucketCount[tid];
    part[tid] = val;
    __syncthreads();
    for (int off = 1; off < 256; off <<= 1) {
        int t = (tid >= off) ? part[tid - off] : 0;
        __syncthreads();
        part[tid] += t;
        __syncthreads();
    }
    int excl = part[tid] - val;
    bucket_base[tid] = excl;
    cursor[tid] = excl;
}

// Pass B: partition edges into coarse buckets (LDS counting sort, run-grouped writes)
__global__ __launch_bounds__(256)
void bucket_scatter_kernel(const int* __restrict__ eidx,
                           int* __restrict__ cursor,
                           int* __restrict__ bucketed, int E) {
    __shared__ int hist[NBUCK];
    __shared__ int lstart[NBUCK];
    __shared__ int gbase[NBUCK];
    __shared__ int part[256];
    __shared__ int stage[PB_CHUNK];
    __shared__ unsigned char stageB[PB_CHUNK];

    int tid = threadIdx.x;
    int start = blockIdx.x * PB_CHUNK;
    int cnt = min(PB_CHUNK, E - start);
    hist[tid] = 0;
    __syncthreads();

    const int J = PB_CHUNK / 256;
    int myP[J], myB[J], myR[J];
    #pragma unroll
    for (int j = 0; j < J; ++j) {
        int idx = j * 256 + tid;
        myR[j] = -1;
        if (idx < cnt) {
            int e = start + idx;
            int d = eidx[E + e];
            int s = eidx[e];
            int b = d >> 9;
            myB[j] = b;
            myP[j] = ((d & 511) << 17) | s;
            myR[j] = atomicAdd(&hist[b], 1);
        }
    }
    __syncthreads();
    part[tid] = hist[tid];
    __syncthreads();
    for (int off = 1; off < 256; off <<= 1) {
        int t = (tid >= off) ? part[tid - off] : 0;
        __syncthreads();
        part[tid] += t;
        __syncthreads();
    }
    lstart[tid] = part[tid] - hist[tid];
    if (hist[tid]) gbase[tid] = atomicAdd(&cursor[tid], hist[tid]);
    __syncthreads();
    #pragma unroll
    for (int j = 0; j < J; ++j) {
        if (myR[j] >= 0) {
            int pos = lstart[myB[j]] + myR[j];
            stage[pos] = myP[j];
            stageB[pos] = (unsigned char)myB[j];
        }
    }
    __syncthreads();
    for (int i = tid; i < cnt; i += 256) {
        int b = stageB[i];
        bucketed[gbase[b] + (i - lstart[b])] = stage[i];
    }
}

// Pass C: per-bucket fine partition -> CSR (offsets = segment start, deg)
__global__ __launch_bounds__(256)
void csr_kernel(const int* __restrict__ bucketed,
                const int* __restrict__ bucket_base,
                const int* __restrict__ cursor_post,
                int* __restrict__ offsets, int* __restrict__ deg,
                int* __restrict__ sorted_src, int N) {
    __shared__ int hist[512];
    __shared__ int pre[512];
    __shared__ int cur[512];
    __shared__ int part[256];
    int b = blockIdx.x;
    int tid = threadIdx.x;
    int start = bucket_base[b];
    int end = cursor_post[b];
    hist[tid] = 0;
    hist[tid + 256] = 0;
    __syncthreads();
    for (int i = start + tid; i < end; i += 256)
        atomicAdd(&hist[bucketed[i] >> 17], 1);
    __syncthreads();
    int a0 = hist[2 * tid], a1 = hist[2 * tid + 1];
    part[tid] = a0 + a1;
    __syncthreads();
    for (int off = 1; off < 256; off <<= 1) {
        int t = (tid >= off) ? part[tid - off] : 0;
        __syncthreads();
        part[tid] += t;
        __syncthreads();
    }
    int base2 = part[tid] - (a0 + a1);
    pre[2 * tid] = base2;
    pre[2 * tid + 1] = base2 + a0;
    cur[2 * tid] = base2;
    cur[2 * tid + 1] = base2 + a0;
    __syncthreads();
    int node0 = b << 9;
    for (int i = tid; i < 512; i += 256) {
        int node = node0 + i;
        if (node < N) { offsets[node] = start + pre[i]; deg[node] = hist[i]; }
    }
    for (int i = start + tid; i < end; i += 256) {
        int p = bucketed[i];
        int ld = p >> 17;
        int src = p & 0x1FFFF;
        int r = atomicAdd(&cur[ld], 1);
        sorted_src[start + r] = src;
    }
}

// Fused gather + MFMA epilogue.
//  Round-2 change: the 16 row-gather loads per chunk are issued via inline-asm
//  global_load_dwordx4 (SGPR base + 32-bit voffset) into 16 NAMED registers,
//  followed by ONE explicit s_waitcnt vmcnt(0) + sched_barrier(0).  This forces
//  MLP=16 (round-1's C-level r[16] was re-fused by the compiler to MLP~1-2,
//  visible as VGPR_Count=68).  All 16 loads are unconditional (addresses use
//  the clamped batch index, always a valid row); the jj<m mask moves into the
//  accumulate as fmaf(val, w, acc) with w in {0,1} -> bitwise-identical sums.
__global__ __launch_bounds__(256, 3)
void gather_epilogue_kernel(const short* __restrict__ v_bf,
                            const int* __restrict__ sorted_src,
                            const int* __restrict__ offsets,
                            const int* __restrict__ deg,
                            const float* __restrict__ W,
                            const float* __restrict__ bias,
                            const float* __restrict__ c_ptr,
                            float* __restrict__ out,
                            int N) {
    __shared__ short Wl[128 * WPITCH];    // 34816 B
    __shared__ short v2l[64 * WPITCH];    // 17408 B  (4 tiles x 16 rows)

    int tid = threadIdx.x;
    // stage W -> LDS bf16 (read once per block from L2)
    for (int i = tid; i < 4096; i += 256) {
        float4 w4 = ((const float4*)W)[i];
        int o = i >> 5;
        int k = (i & 31) * 4;
        bf16x4 w;
        w[0] = f2bf(w4.x); w[1] = f2bf(w4.y); w[2] = f2bf(w4.z); w[3] = f2bf(w4.w);
        *(bf16x4*)&Wl[o * WPITCH + k] = w;
    }

    int wave = tid >> 6;
    int lane = tid & 63;
    int quad = lane >> 4;
    int l16  = lane & 15;
    int g  = tid >> 4;        // gather group (0..15)
    int gl = tid & 15;        // lane in group
    float sc = sqrtf(c_ptr[0]);

    // per-lane bias for the 8 col-tiles this wave's rows need (col = c*16+l16)
    float bsv[8];
    #pragma unroll
    for (int c = 0; c < 8; ++c) bsv[c] = bias[c * 16 + l16];

    int row_base = blockIdx.x * 64;

    // ---- gather phase: 4 rows per group, barrier-free ----
    for (int t = 0; t < 4; ++t) {
        int row = row_base + t * 16 + g;
        bool valid = (row < N);
        float acc[8];
        #pragma unroll
        for (int i = 0; i < 8; ++i) acc[i] = 0.0f;
        int start = 0, d = 0;
        if (valid) {
            start = offsets[row];
            d = deg[row];
            bf16x8 r0 = *(const bf16x8*)&v_bf[(size_t)row * 128 + gl * 8];
            i32x4 w0 = *(const i32x4*)&r0;
            #pragma unroll
            for (int k2 = 0; k2 < 4; ++k2) {
                acc[2 * k2]     = bf_lo(w0[k2]);
                acc[2 * k2 + 1] = bf_hi(w0[k2]);
            }
        }
        for (int j = 0; j < d; j += 16) {
            int m = d - j;                              // group-uniform
            // clamped edge index: every lane's batch is a VALID src row
            int batch = sorted_src[start + min(j + gl, d - 1)];

            bf16x8 q0, q1, q2, q3, q4, q5, q6, q7,
                   q8, q9, qA, qB, qC, qD, qE, qF;
#define GLD(i, dst) do {                                                      \
        int src_ = __shfl(batch, (lane & 48) | (i));                          \
        unsigned voff_ = ((unsigned)src_ << 8) | (unsigned)(gl << 4);         \
        asm volatile("global_load_dwordx4 %0, %1, %2"                         \
                     : "=v"(dst) : "v"(voff_), "s"(v_bf));                    \
    } while (0)
            GLD(0, q0);  GLD(1, q1);  GLD(2, q2);  GLD(3, q3);
            GLD(4, q4);  GLD(5, q5);  GLD(6, q6);  GLD(7, q7);
            GLD(8, q8);  GLD(9, q9);  GLD(10, qA); GLD(11, qB);
            GLD(12, qC); GLD(13, qD); GLD(14, qE); GLD(15, qF);
#undef GLD
            asm volatile("s_waitcnt vmcnt(0)" ::: "memory");
            __builtin_amdgcn_sched_barrier(0);   // keep FMAs below the waitcnt

#define ACC(i, rsrc) do {                                                     \
        float w_ = ((i) < m) ? 1.0f : 0.0f;                                   \
        i32x4 wv_ = *(i32x4*)&(rsrc);                                         \
        acc[0] = fmaf(bf_lo(wv_[0]), w_, acc[0]);                             \
        acc[1] = fmaf(bf_hi(wv_[0]), w_, acc[1]);                             \
        acc[2] = fmaf(bf_lo(wv_[1]), w_, acc[2]);                             \
        acc[3] = fmaf(bf_hi(wv_[1]), w_, acc[3]);                             \
        acc[4] = fmaf(bf_lo(wv_[2]), w_, acc[4]);                             \
        acc[5] = fmaf(bf_hi(wv_[2]), w_, acc[5]);                             \
        acc[6] = fmaf(bf_lo(wv_[3]), w_, acc[6]);                             \
        acc[7] = fmaf(bf_hi(wv_[3]), w_, acc[7]);                             \
    } while (0)
            ACC(0, q0);  ACC(1, q1);  ACC(2, q2);  ACC(3, q3);
            ACC(4, q4);  ACC(5, q5);  ACC(6, q6);  ACC(7, q7);
            ACC(8, q8);  ACC(9, q9);  ACC(10, qA); ACC(11, qB);
            ACC(12, qC); ACC(13, qD); ACC(14, qE); ACC(15, qF);
#undef ACC
        }
        float inv = 1.0f / (float)(d + 1);
        #pragma unroll
        for (int i = 0; i < 8; ++i) acc[i] *= inv;

        // row sumsq across the 16-lane group
        float ss = 0.0f;
        #pragma unroll
        for (int i = 0; i < 8; ++i) ss += acc[i] * acc[i];
        ss += __shfl_xor(ss, 1);
        ss += __shfl_xor(ss, 2);
        ss += __shfl_xor(ss, 4);
        ss += __shfl_xor(ss, 8);

        // exp_map_zero then log_map_zero scale (redundant per lane)
        float vn  = sqrtf(ss);
        float vnc = fmaxf(vn, EPSF);
        float th  = tanhf(sc * vnc);
        float tt  = th / (sc * vnc);          // x_hyp = tt * v_agg
        float hn  = fmaxf(th / sc, EPSF);
        float y2  = fminf(sc * hn, YMAXF);
        float s2  = atanhf(y2) / (sc * hn);   // v2 = s2 * x_hyp
        float scale = s2 * tt;

        bf16x8 pk;
        #pragma unroll
        for (int i = 0; i < 8; ++i) pk[i] = f2bf(acc[i] * scale);
        *(bf16x8*)&v2l[(t * 16 + g) * WPITCH + gl * 8] = pk;
    }
    __syncthreads();

    // ---- MFMA phase: wave w owns tile w (16 rows x 128 cols) ----
    f32x4 acc2[8];
    #pragma unroll
    for (int c = 0; c < 8; ++c) acc2[c] = (f32x4){bsv[c], bsv[c], bsv[c], bsv[c]};
    #pragma unroll
    for (int k0 = 0; k0 < 128; k0 += 32) {
        bf16x8 af = *(const bf16x8*)&v2l[(wave * 16 + l16) * WPITCH + k0 + quad * 8];
        #pragma unroll
        for (int c = 0; c < 8; ++c) {
            bf16x8 bf = *(const bf16x8*)&Wl[(c * 16 + l16) * WPITCH + k0 + quad * 8];
            acc2[c] = __builtin_amdgcn_mfma_f32_16x16x32_bf16(af, bf, acc2[c], 0, 0, 0);
        }
    }

    // out-norm + exp_map store, fully in-wave: D(row=quad*4+r, col=c*16+l16)
    #pragma unroll
    for (int r = 0; r < 4; ++r) {
        float ss = 0.0f;
        #pragma unroll
        for (int c = 0; c < 8; ++c) ss += acc2[c][r] * acc2[c][r];
        ss += __shfl_xor(ss, 1);
        ss += __shfl_xor(ss, 2);
        ss += __shfl_xor(ss, 4);
        ss += __shfl_xor(ss, 8);
        float on  = sqrtf(ss);
        float onc = fmaxf(on, EPSF);
        float gsc = tanhf(sc * onc) / (sc * onc);
        int orow = row_base + wave * 16 + quad * 4 + r;
        if (orow < N) {
            size_t base = (size_t)orow * 128;
            #pragma unroll
            for (int c = 0; c < 8; ++c)
                out[base + c * 16 + l16] = gsc * acc2[c][r];
        }
    }
}

extern "C" void kernel_launch(void* const* d_in, const int* in_sizes, int n_in,
                              void* d_out, int out_size, void* d_ws, size_t ws_size,
                              hipStream_t stream) {
    const float* x     = (const float*)d_in[0];
    const int*   eidx  = (const int*)d_in[1];
    const float* c_ptr = (const float*)d_in[2];
    const float* W     = (const float*)d_in[4];
    const float* bias  = (const float*)d_in[5];
    float* out = (float*)d_out;

    int N = in_sizes[0] / 128;
    int E = in_sizes[1] / 2;

    short* v_bf        = (short*)d_ws;                     // N*128 bf16
    int*   deg         = (int*)(v_bf + (size_t)N * 128);   // N
    int*   offsets     = deg + N;                          // N
    int*   bucketCount = offsets + N;                      // NBUCK
    int*   bucket_base = bucketCount + NBUCK;              // NBUCK
    int*   cursor      = bucket_base + NBUCK;              // NBUCK
    int*   bucketed    = cursor + NBUCK;                   // E (packed)
    int*   sorted_src  = bucketed + E;                     // E

    hipMemsetAsync(bucketCount, 0, NBUCK * sizeof(int), stream);

    {
        long long threads = (long long)N * 32;
        int blocks = (int)((threads + 255) / 256);
        hipLaunchKernelGGL(logmap_kernel, dim3(blocks), dim3(256), 0, stream,
                           x, c_ptr, v_bf, N);
    }
    hipLaunchKernelGGL(bucket_count_kernel, dim3(256), dim3(256), 0, stream,
                       eidx + E, bucketCount, E);
    hipLaunchKernelGGL(bucket_scan_kernel, dim3(1), dim3(256), 0, stream,
                       bucketCount, bucket_base, cursor);
    {
        int blocks = (E + PB_CHUNK - 1) / PB_CHUNK;
        hipLaunchKernelGGL(bucket_scatter_kernel, dim3(blocks), dim3(256), 0, stream,
                           eidx, cursor, bucketed, E);
    }
    {
        int blocks = (N + 511) / 512;
        hipLaunchKernelGGL(csr_kernel, dim3(blocks), dim3(256), 0, stream,
                           bucketed, bucket_base, cursor, offsets, deg, sorted_src, N);
    }
    {
        int blocks = (N + 63) / 64;
        hipLaunchKernelGGL(gather_epilogue_kernel, dim3(blocks), dim3(256), 0, stream,
                           v_bf, sorted_src, offsets, deg, W, bias, c_ptr, out, N);
    }
}